// Round 8
// baseline (245.571 us; speedup 1.0000x reference)
//
#include <hip/hip_runtime.h>
#include <hip/hip_fp16.h>
#include <type_traits>

// 3-layer GCN encoder on MI355X.
//   CSR build: bin (bucket by dst>>8, packed src|localdst<<16) ->
//              build_csr (fused bucket-scan + LDS histogram + block scan -> off/dinv,
//                         then in-LDS scatter -> col)
//   gemm1: g1 = (x @ W1) * dinv                     [fp16 out]
//   fused agg_gemm (x2): h = tanh(dinv*sum g[s] + b); g' = (h @ W') * dinv
//       - after the shfl_xor butterfly every lane holds its 8-elem chunk of h;
//         wave-broadcast via compile-time __shfl (v_readlane), W in LDS.
//   agg3: z = dinv*sum g3[s] + b3 -> f32 out
// R8: agg+gemm fusion (9 -> 7 dispatches, bufH round-trip eliminated, h stays f32);
//     gather unroll 4; fused kernels grid-stride at 2048 blocks.
// NOTE: packing assumes N <= 65535 (here N=50000).

#define IN_DIM 64
#define HID_DIM 64
#define LAT_DIM 32
#define BCAP 5120   // bucket capacity: mean 4081, sigma ~64 -> +16 sigma

typedef __attribute__((ext_vector_type(8))) _Float16 half8;
typedef __attribute__((ext_vector_type(4))) _Float16 half4;

// ---------------- bucketed CSR construction ----------------

__global__ __launch_bounds__(256) void bin_kernel(const int* __restrict__ src,
                                                  const int* __restrict__ dst,
                                                  int* __restrict__ bucket_cnt,
                                                  unsigned* __restrict__ pairs, int E) {
    __shared__ int bcnt[256];
    __shared__ int bbase[256];
    int tid = threadIdx.x;
    bcnt[tid] = 0;
    __syncthreads();
    int base = blockIdx.x * 4096;
    unsigned pk[16]; int bk[16]; int rk[16];
    #pragma unroll
    for (int i = 0; i < 16; ++i) {
        int e = base + i * 256 + tid;
        bk[i] = -1;
        if (e < E) {
            int s = __builtin_nontemporal_load(src + e);
            int d = __builtin_nontemporal_load(dst + e);
            bk[i] = d >> 8;
            pk[i] = (unsigned)s | ((unsigned)(d & 255) << 16);
            rk[i] = atomicAdd(&bcnt[bk[i]], 1);
        }
    }
    __syncthreads();
    int c = bcnt[tid];
    if (c > 0) bbase[tid] = atomicAdd(&bucket_cnt[tid], c);
    __syncthreads();
    #pragma unroll
    for (int i = 0; i < 16; ++i) {
        if (bk[i] >= 0) {
            int pos = bbase[bk[i]] + rk[i];
            if (pos < BCAP) pairs[(size_t)bk[i] * BCAP + pos] = pk[i];
        }
    }
}

// Fused: (A) every block scans all bucket counts in LDS (cheap, redundant),
// (B) per-bucket node histogram, (C) block scan -> off/dinv, (D) in-LDS scatter.
__global__ __launch_bounds__(256) void build_csr_kernel(const unsigned* __restrict__ pairs,
                                                        const int* __restrict__ bucket_cnt,
                                                        int* __restrict__ off,
                                                        float* __restrict__ dinv,
                                                        int* __restrict__ col,
                                                        int N, int NBK) {
    __shared__ int sboff[256];
    __shared__ int h[256];
    __shared__ int scur[256];
    __shared__ int wtot[4];
    int b = blockIdx.x, tid = threadIdx.x;
    int lane = tid & 63, wid = tid >> 6;

    // A: exclusive scan of bucket counts
    int v = (tid < NBK) ? min(bucket_cnt[tid], BCAP) : 0;
    int sc = v;
    #pragma unroll
    for (int d = 1; d < 64; d <<= 1) {
        int t = __shfl_up(sc, d, 64);
        if (lane >= d) sc += t;
    }
    if (lane == 63) wtot[wid] = sc;
    h[tid] = 0;
    __syncthreads();
    int woff = 0;
    #pragma unroll
    for (int w = 0; w < 4; ++w) if (w < wid) woff += wtot[w];
    sboff[tid] = woff + sc - v;
    __syncthreads();
    int boff_b = sboff[b];

    // B: histogram of this bucket's local dst
    int c = min(bucket_cnt[b], BCAP);
    const unsigned* pb = pairs + (size_t)b * BCAP;
    for (int i = tid; i < c; i += 256)
        atomicAdd(&h[pb[i] >> 16], 1);
    __syncthreads();

    // C: block scan of histogram -> off / dinv / scur
    int hv = h[tid];
    int sc2 = hv;
    #pragma unroll
    for (int d = 1; d < 64; d <<= 1) {
        int t = __shfl_up(sc2, d, 64);
        if (lane >= d) sc2 += t;
    }
    if (lane == 63) wtot[wid] = sc2;
    __syncthreads();
    int woff2 = 0;
    #pragma unroll
    for (int w = 0; w < 4; ++w) if (w < wid) woff2 += wtot[w];
    int incl = woff2 + sc2;
    int node = b * 256 + tid;
    scur[tid] = boff_b + incl - hv;
    if (node < N) {
        off[node + 1] = boff_b + incl;
        dinv[node]    = rsqrtf((float)(hv + 1));
    }
    if (b == 0 && tid == 0) off[0] = 0;
    __syncthreads();

    // D: scatter (col writes land in this bucket's contiguous window)
    for (int i = tid; i < c; i += 256) {
        unsigned p = pb[i];
        int pos = atomicAdd(&scur[p >> 16], 1);
        col[pos] = (int)(p & 0xFFFFu);
    }
}

// ---------------- GEMM (N x 64) @ (64 x OUT) * dinv[row] -> fp16 G ----------------

template<int OUT, int RT>
__global__ __launch_bounds__(256) void gemm_tile_kernel(const float* __restrict__ X,
                                                        const float* __restrict__ W,
                                                        const float* __restrict__ dinv,
                                                        _Float16* __restrict__ G, int N) {
    constexpr int CG = OUT / 4;
    static_assert(256 / CG * 4 == RT, "RT must match 4*(256/CG)");
    __shared__ float Ws[64 * OUT];
    __shared__ float Xs[RT][64 + 4];
    int tid = threadIdx.x;
    int row0 = blockIdx.x * RT;

    for (int f = 4 * tid; f < 64 * OUT; f += 1024)
        *(float4*)&Ws[f] = *(const float4*)&W[f];

    for (int f = 4 * tid; f < RT * 64; f += 1024) {
        int r = f >> 6, k0 = f & 63, gr = row0 + r;
        float4 v = (gr < N) ? *(const float4*)&X[(size_t)gr * 64 + k0]
                            : make_float4(0.f, 0.f, 0.f, 0.f);
        *(float4*)&Xs[r][k0] = v;
    }
    __syncthreads();

    int cr = tid % CG;
    int rr = tid / CG;
    float acc[4][4] = {};
    #pragma unroll 4
    for (int k = 0; k < 64; ++k) {
        float4 bv = *(float4*)&Ws[k * OUT + 4 * cr];
        float av[4] = {Xs[4 * rr + 0][k], Xs[4 * rr + 1][k],
                       Xs[4 * rr + 2][k], Xs[4 * rr + 3][k]};
        float bb[4] = {bv.x, bv.y, bv.z, bv.w};
        #pragma unroll
        for (int j = 0; j < 4; ++j)
            #pragma unroll
            for (int i = 0; i < 4; ++i)
                acc[j][i] += av[j] * bb[i];
    }

    #pragma unroll
    for (int j = 0; j < 4; ++j) {
        int gr = row0 + 4 * rr + j;
        if (gr < N) {
            float s = dinv[gr];
            half4 o;
            #pragma unroll
            for (int i = 0; i < 4; ++i) o[i] = (_Float16)(acc[j][i] * s);
            *(half4*)&G[(size_t)gr * OUT + 4 * cr] = o;
        }
    }
}

// ---------------- fused AGG + next-layer GEMM ----------------
// One wave per node (grid-stride). Gather fp16 rows (8 slots x 8 chunks), butterfly
// reduce -> every lane holds its 8-elem chunk of agg. All lanes compute
// h[chunk] = tanh(dinv*acc + b). Wave-broadcast h via compile-time __shfl
// (v_readlane) and each lane computes one output column of h @ W (W in LDS;
// 2-way bank access = free). Output g' = dinv * (h @ W) as fp16, 2B/lane store.

template<int DOUT>
__global__ __launch_bounds__(256) void agg_gemm_kernel(const _Float16* __restrict__ G,
                            const int* __restrict__ off, const int* __restrict__ col,
                            const float* __restrict__ dinv, const float* __restrict__ bias,
                            const float* __restrict__ W, _Float16* __restrict__ G2,
                            int N) {
    __shared__ float Ws[64 * DOUT];
    int tid = threadIdx.x;
    for (int f = 4 * tid; f < 64 * DOUT; f += 1024)
        *(float4*)&Ws[f] = *(const float4*)&W[f];
    __syncthreads();

    int lane = tid & 63, w = tid >> 6;
    int grp = lane >> 3, c4 = lane & 7;
    int stride = gridDim.x * 4;

    for (int node = blockIdx.x * 4 + w; node < N; node += stride) {
        int p0 = off[node];
        int total = off[node + 1] - p0 + 1;   // + self loop
        float acc[8] = {};
        #pragma unroll 4
        for (int base = 0; base < total; base += 8) {
            int e = base + grp;
            if (e < total) {
                int s = (e == 0) ? node : col[p0 + e - 1];
                half8 u = *(const half8*)&G[(size_t)s * 64 + 8 * c4];
                #pragma unroll
                for (int i = 0; i < 8; ++i) acc[i] += (float)u[i];
            }
        }
        #pragma unroll
        for (int m = 8; m < 64; m <<= 1) {
            #pragma unroll
            for (int i = 0; i < 8; ++i) acc[i] += __shfl_xor(acc[i], m, 64);
        }
        // h chunk for every lane (replicated across grp)
        float dn = dinv[node];
        float o[8];
        #pragma unroll
        for (int i = 0; i < 8; ++i) o[i] = tanhf(dn * acc[i] + bias[8 * c4 + i]);

        // gemm: h (broadcast via readlane) @ W
        float outv = 0.f;
        if constexpr (DOUT == 64) {
            int c = lane;
            #pragma unroll
            for (int k = 0; k < 64; ++k) {
                float hk = __shfl(o[k & 7], k >> 3, 64);  // lane j<8 holds chunk j
                outv += hk * Ws[k * 64 + c];
            }
        } else {  // DOUT == 32: lane -> (col = lane&31, k-half = lane>>5)
            int c = lane & 31, kh = lane >> 5;
            #pragma unroll
            for (int kk = 0; kk < 32; ++kk) {
                int k = kh * 32 + kk;
                float hk = __shfl(o[k & 7], k >> 3, 64);
                outv += hk * Ws[k * DOUT + c];
            }
            outv += __shfl_xor(outv, 32, 64);
        }
        outv *= dn;
        if (DOUT == 64 || lane < 32)
            G2[(size_t)node * DOUT + (DOUT == 64 ? lane : (lane & 31))] = (_Float16)outv;
    }
}

// ---------------- final CSR aggregation (fp16 gather -> f32 out) ----------------

template<int D>
__global__ __launch_bounds__(256) void agg_kernel(const _Float16* __restrict__ G,
                           const int* __restrict__ off,
                           const int* __restrict__ col, const float* __restrict__ dinv,
                           const float* __restrict__ b, float* __restrict__ H, int N) {
    constexpr int CHUNKS = D / 8;          // 4 for D=32
    constexpr int EPI = 64 / CHUNKS;       // 16 edge slots per iter
    int tid  = threadIdx.x;
    int lane = tid & 63;
    int w    = tid >> 6;
    int node = blockIdx.x * 4 + w;
    if (node >= N) return;
    int grp = lane / CHUNKS;
    int c4  = lane % CHUNKS;
    int p0  = off[node];
    int total = off[node + 1] - p0 + 1;
    float acc[8] = {};
    #pragma unroll 4
    for (int base = 0; base < total; base += EPI) {
        int e = base + grp;
        if (e < total) {
            int s = (e == 0) ? node : col[p0 + e - 1];
            half8 u = *(const half8*)&G[(size_t)s * D + 8 * c4];
            #pragma unroll
            for (int i = 0; i < 8; ++i) acc[i] += (float)u[i];
        }
    }
    #pragma unroll
    for (int m = CHUNKS; m < 64; m <<= 1) {
        #pragma unroll
        for (int i = 0; i < 8; ++i) acc[i] += __shfl_xor(acc[i], m, 64);
    }
    if (grp == 0) {
        float s = dinv[node];
        float4 f0, f1;
        f0.x = s * acc[0] + b[8 * c4 + 0]; f0.y = s * acc[1] + b[8 * c4 + 1];
        f0.z = s * acc[2] + b[8 * c4 + 2]; f0.w = s * acc[3] + b[8 * c4 + 3];
        f1.x = s * acc[4] + b[8 * c4 + 4]; f1.y = s * acc[5] + b[8 * c4 + 5];
        f1.z = s * acc[6] + b[8 * c4 + 6]; f1.w = s * acc[7] + b[8 * c4 + 7];
        *(float4*)&H[(size_t)node * D + 8 * c4 + 0] = f0;
        *(float4*)&H[(size_t)node * D + 8 * c4 + 4] = f1;
    }
}

// ---------------- launch ----------------

static inline size_t align256(size_t x) { return (x + 255) & ~(size_t)255; }

extern "C" void kernel_launch(void* const* d_in, const int* in_sizes, int n_in,
                              void* d_out, int out_size, void* d_ws, size_t ws_size,
                              hipStream_t stream) {
    const float* x   = (const float*)d_in[0];
    const int*   ei  = (const int*)d_in[1];
    const float* W1  = (const float*)d_in[2];
    const float* b1  = (const float*)d_in[3];
    const float* W2  = (const float*)d_in[4];
    const float* b2  = (const float*)d_in[5];
    const float* W3  = (const float*)d_in[6];
    const float* b3  = (const float*)d_in[7];
    float* out = (float*)d_out;

    const int N = in_sizes[0] / IN_DIM;   // 50000
    const int E = in_sizes[1] / 2;        // 800000
    const int* src = ei;
    const int* dst = ei + E;
    const int NBK  = (N + 255) / 256;     // buckets (196)
    const int BINB = (E + 4095) / 4096;   // bin blocks (196)

    // workspace layout
    char* ws = (char*)d_ws;
    size_t o = 0;
    int*       bkcnt = (int*)(ws + o);       o = align256(o + 256 * 4);
    int*       off   = (int*)(ws + o);       o = align256(o + (size_t)(N + 1) * 4);
    float*     dinv  = (float*)(ws + o);     o = align256(o + (size_t)N * 4);
    unsigned*  pairs = (unsigned*)(ws + o);  o = align256(o + (size_t)NBK * BCAP * 4);
    int*       col   = (int*)(ws + o);       o = align256(o + (size_t)E * 4);
    _Float16*  bufG  = (_Float16*)(ws + o);  o = align256(o + (size_t)N * HID_DIM * 2);
    _Float16*  bufG2 = (_Float16*)(ws + o);  o = align256(o + (size_t)N * HID_DIM * 2);
    (void)ws_size;

    // CSR build
    hipMemsetAsync(bkcnt, 0, 256 * 4, stream);
    bin_kernel<<<BINB, 256, 0, stream>>>(src, dst, bkcnt, pairs, E);
    build_csr_kernel<<<NBK, 256, 0, stream>>>(pairs, bkcnt, off, dinv, col, N, NBK);

    const int g64_grid = (N + 63) / 64;    // RT=64
    const int agg_grid = (N + 3) / 4;      // 1 node/wave, 4 waves/block
    const int fus_grid = 2048;             // grid-stride, ~7 blocks/CU

    // layer 1 GEMM: g1 = (x @ W1) * dinv
    gemm_tile_kernel<HID_DIM, 64><<<g64_grid, 256, 0, stream>>>(x, W1, dinv, bufG, N);
    // fused: h1 = tanh(dinv*agg(g1)+b1); g2 = (h1 @ W2) * dinv
    agg_gemm_kernel<64><<<fus_grid, 256, 0, stream>>>(bufG, off, col, dinv, b1, W2, bufG2, N);
    // fused: h2 = tanh(dinv*agg(g2)+b2); g3 = (h2 @ W3) * dinv
    agg_gemm_kernel<32><<<fus_grid, 256, 0, stream>>>(bufG2, off, col, dinv, b2, W3, bufG, N);
    // final: z = dinv*agg(g3) + b3
    agg_kernel<LAT_DIM><<<agg_grid, 256, 0, stream>>>(bufG, off, col, dinv, b3, out, N);
}

// Round 10
// 225.838 us; speedup vs baseline: 1.0874x; 1.0874x over previous
//
#include <hip/hip_runtime.h>
#include <hip/hip_fp16.h>
#include <type_traits>

// 3-layer GCN encoder on MI355X.
//   CSR build: bin (bucket by dst>>8, packed src|localdst<<16) ->
//              build_csr (fused bucket-scan + LDS histogram + block scan -> off/dinv,
//                         then in-LDS scatter -> col)
//   Per layer: g = (h @ W) * dinv [fp16] ; h = act(dinv * sum_{N(d)+self} g[s] + b)
// R9 (resubmit; prior bench failed on GPU acquisition):
//     UN-fuse agg+gemm (R8 regression: serial readlane-GEMM + 48-shfl butterfly
//     made agg VALU-issue-bound, 67us). New agg: lane=column, zero cross-lane ops,
//     2 VALU/edge/lane, 4 accumulators. Separate tiled GEMMs (measured ~10us).
// NOTE: packing assumes N <= 65535 (here N=50000).

#define IN_DIM 64
#define HID_DIM 64
#define LAT_DIM 32
#define BCAP 5120   // bucket capacity: mean 4081, sigma ~64 -> +16 sigma

typedef __attribute__((ext_vector_type(8))) _Float16 half8;
typedef __attribute__((ext_vector_type(4))) _Float16 half4;

// ---------------- bucketed CSR construction ----------------

__global__ __launch_bounds__(256) void bin_kernel(const int* __restrict__ src,
                                                  const int* __restrict__ dst,
                                                  int* __restrict__ bucket_cnt,
                                                  unsigned* __restrict__ pairs, int E) {
    __shared__ int bcnt[256];
    __shared__ int bbase[256];
    int tid = threadIdx.x;
    bcnt[tid] = 0;
    __syncthreads();
    int base = blockIdx.x * 4096;
    unsigned pk[16]; int bk[16]; int rk[16];
    #pragma unroll
    for (int i = 0; i < 16; ++i) {
        int e = base + i * 256 + tid;
        bk[i] = -1;
        if (e < E) {
            int s = __builtin_nontemporal_load(src + e);
            int d = __builtin_nontemporal_load(dst + e);
            bk[i] = d >> 8;
            pk[i] = (unsigned)s | ((unsigned)(d & 255) << 16);
            rk[i] = atomicAdd(&bcnt[bk[i]], 1);
        }
    }
    __syncthreads();
    int c = bcnt[tid];
    if (c > 0) bbase[tid] = atomicAdd(&bucket_cnt[tid], c);
    __syncthreads();
    #pragma unroll
    for (int i = 0; i < 16; ++i) {
        if (bk[i] >= 0) {
            int pos = bbase[bk[i]] + rk[i];
            if (pos < BCAP) pairs[(size_t)bk[i] * BCAP + pos] = pk[i];
        }
    }
}

// Fused: (A) every block scans all bucket counts in LDS (cheap, redundant),
// (B) per-bucket node histogram, (C) block scan -> off/dinv, (D) in-LDS scatter.
__global__ __launch_bounds__(256) void build_csr_kernel(const unsigned* __restrict__ pairs,
                                                        const int* __restrict__ bucket_cnt,
                                                        int* __restrict__ off,
                                                        float* __restrict__ dinv,
                                                        int* __restrict__ col,
                                                        int N, int NBK) {
    __shared__ int sboff[256];
    __shared__ int h[256];
    __shared__ int scur[256];
    __shared__ int wtot[4];
    int b = blockIdx.x, tid = threadIdx.x;
    int lane = tid & 63, wid = tid >> 6;

    // A: exclusive scan of bucket counts
    int v = (tid < NBK) ? min(bucket_cnt[tid], BCAP) : 0;
    int sc = v;
    #pragma unroll
    for (int d = 1; d < 64; d <<= 1) {
        int t = __shfl_up(sc, d, 64);
        if (lane >= d) sc += t;
    }
    if (lane == 63) wtot[wid] = sc;
    h[tid] = 0;
    __syncthreads();
    int woff = 0;
    #pragma unroll
    for (int w = 0; w < 4; ++w) if (w < wid) woff += wtot[w];
    sboff[tid] = woff + sc - v;
    __syncthreads();
    int boff_b = sboff[b];

    // B: histogram of this bucket's local dst
    int c = min(bucket_cnt[b], BCAP);
    const unsigned* pb = pairs + (size_t)b * BCAP;
    for (int i = tid; i < c; i += 256)
        atomicAdd(&h[pb[i] >> 16], 1);
    __syncthreads();

    // C: block scan of histogram -> off / dinv / scur
    int hv = h[tid];
    int sc2 = hv;
    #pragma unroll
    for (int d = 1; d < 64; d <<= 1) {
        int t = __shfl_up(sc2, d, 64);
        if (lane >= d) sc2 += t;
    }
    if (lane == 63) wtot[wid] = sc2;
    __syncthreads();
    int woff2 = 0;
    #pragma unroll
    for (int w = 0; w < 4; ++w) if (w < wid) woff2 += wtot[w];
    int incl = woff2 + sc2;
    int node = b * 256 + tid;
    scur[tid] = boff_b + incl - hv;
    if (node < N) {
        off[node + 1] = boff_b + incl;
        dinv[node]    = rsqrtf((float)(hv + 1));
    }
    if (b == 0 && tid == 0) off[0] = 0;
    __syncthreads();

    // D: scatter (col writes land in this bucket's contiguous window)
    for (int i = tid; i < c; i += 256) {
        unsigned p = pb[i];
        int pos = atomicAdd(&scur[p >> 16], 1);
        col[pos] = (int)(p & 0xFFFFu);
    }
}

// ---------------- GEMM (N x 64) @ (64 x OUT) * dinv[row] -> fp16 G ----------------
// Row-major X staging (coalesced). 4x4 outputs/thread; a-reads are 16-lane
// broadcasts (free), b-read one 2-way b128 (free).

template<int OUT, int RT, typename TIN>
__global__ __launch_bounds__(256) void gemm_tile_kernel(const TIN* __restrict__ X,
                                                        const float* __restrict__ W,
                                                        const float* __restrict__ dinv,
                                                        _Float16* __restrict__ G, int N) {
    constexpr int CG = OUT / 4;
    static_assert(256 / CG * 4 == RT, "RT must match 4*(256/CG)");
    __shared__ float Ws[64 * OUT];
    __shared__ float Xs[RT][64 + 4];
    int tid = threadIdx.x;
    int row0 = blockIdx.x * RT;

    for (int f = 4 * tid; f < 64 * OUT; f += 1024)
        *(float4*)&Ws[f] = *(const float4*)&W[f];

    if constexpr (std::is_same<TIN, float>::value) {
        for (int f = 4 * tid; f < RT * 64; f += 1024) {
            int r = f >> 6, k0 = f & 63, gr = row0 + r;
            float4 v = (gr < N) ? *(const float4*)&X[(size_t)gr * 64 + k0]
                                : make_float4(0.f, 0.f, 0.f, 0.f);
            *(float4*)&Xs[r][k0] = v;
        }
    } else {
        for (int f = 8 * tid; f < RT * 64; f += 2048) {
            int r = f >> 6, k0 = f & 63, gr = row0 + r;
            if (gr < N) {
                half8 v = *(const half8*)&X[(size_t)gr * 64 + k0];
                #pragma unroll
                for (int i = 0; i < 8; ++i) Xs[r][k0 + i] = (float)v[i];
            } else {
                #pragma unroll
                for (int i = 0; i < 8; ++i) Xs[r][k0 + i] = 0.f;
            }
        }
    }
    __syncthreads();

    int cr = tid % CG;
    int rr = tid / CG;
    float acc[4][4] = {};
    #pragma unroll 4
    for (int k = 0; k < 64; ++k) {
        float4 bv = *(float4*)&Ws[k * OUT + 4 * cr];
        float av[4] = {Xs[4 * rr + 0][k], Xs[4 * rr + 1][k],
                       Xs[4 * rr + 2][k], Xs[4 * rr + 3][k]};
        float bb[4] = {bv.x, bv.y, bv.z, bv.w};
        #pragma unroll
        for (int j = 0; j < 4; ++j)
            #pragma unroll
            for (int i = 0; i < 4; ++i)
                acc[j][i] += av[j] * bb[i];
    }

    #pragma unroll
    for (int j = 0; j < 4; ++j) {
        int gr = row0 + 4 * rr + j;
        if (gr < N) {
            float s = dinv[gr];
            half4 o;
            #pragma unroll
            for (int i = 0; i < 4; ++i) o[i] = (_Float16)(acc[j][i] * s);
            *(half4*)&G[(size_t)gr * OUT + 4 * cr] = o;
        }
    }
}

// ---------------- CSR aggregation, lane = column (no cross-lane ops) ----------------
// D=64: one wave per node, lane l owns column l. Serial edge loop, 4 accumulators.
// Per edge per lane: 1 ushort load (wave reads a contiguous 128B row) + cvt + add.
// col[p] reads are wave-uniform -> broadcast. Self loop folded in as first term.

template<bool TANH>
__global__ __launch_bounds__(256) void agg64_kernel(const _Float16* __restrict__ G,
                           const int* __restrict__ off, const int* __restrict__ col,
                           const float* __restrict__ dinv, const float* __restrict__ b,
                           _Float16* __restrict__ H, int N) {
    int tid  = threadIdx.x;
    int lane = tid & 63;
    int w    = tid >> 6;
    int node = blockIdx.x * 4 + w;
    if (node >= N) return;
    int p  = off[node];
    int p1 = off[node + 1];
    float a0 = (float)G[(size_t)node * 64 + lane];   // self loop
    float a1 = 0.f, a2 = 0.f, a3 = 0.f;
    for (; p + 3 < p1; p += 4) {
        int s0 = col[p], s1 = col[p + 1], s2 = col[p + 2], s3 = col[p + 3];
        a0 += (float)G[(size_t)s0 * 64 + lane];
        a1 += (float)G[(size_t)s1 * 64 + lane];
        a2 += (float)G[(size_t)s2 * 64 + lane];
        a3 += (float)G[(size_t)s3 * 64 + lane];
    }
    for (; p < p1; ++p) a0 += (float)G[(size_t)col[p] * 64 + lane];
    float v = dinv[node] * ((a0 + a1) + (a2 + a3)) + b[lane];
    if (TANH) v = tanhf(v);
    H[(size_t)node * 64 + lane] = (_Float16)v;
}

// D=32 final layer: two nodes per wave (lanes 0-31 / 32-63), f32 output.
__global__ __launch_bounds__(256) void agg32_kernel(const _Float16* __restrict__ G,
                           const int* __restrict__ off, const int* __restrict__ col,
                           const float* __restrict__ dinv, const float* __restrict__ b,
                           float* __restrict__ H, int N) {
    int tid  = threadIdx.x;
    int lane = tid & 63;
    int w    = tid >> 6;
    int node = blockIdx.x * 8 + w * 2 + (lane >> 5);
    int c    = lane & 31;
    if (node >= N) return;
    int p  = off[node];
    int p1 = off[node + 1];
    float a0 = (float)G[(size_t)node * 32 + c];      // self loop
    float a1 = 0.f, a2 = 0.f, a3 = 0.f;
    for (; p + 3 < p1; p += 4) {
        int s0 = col[p], s1 = col[p + 1], s2 = col[p + 2], s3 = col[p + 3];
        a0 += (float)G[(size_t)s0 * 32 + c];
        a1 += (float)G[(size_t)s1 * 32 + c];
        a2 += (float)G[(size_t)s2 * 32 + c];
        a3 += (float)G[(size_t)s3 * 32 + c];
    }
    for (; p < p1; ++p) a0 += (float)G[(size_t)col[p] * 32 + c];
    float v = dinv[node] * ((a0 + a1) + (a2 + a3)) + b[c];
    H[(size_t)node * 32 + c] = v;
}

// ---------------- launch ----------------

static inline size_t align256(size_t x) { return (x + 255) & ~(size_t)255; }

extern "C" void kernel_launch(void* const* d_in, const int* in_sizes, int n_in,
                              void* d_out, int out_size, void* d_ws, size_t ws_size,
                              hipStream_t stream) {
    const float* x   = (const float*)d_in[0];
    const int*   ei  = (const int*)d_in[1];
    const float* W1  = (const float*)d_in[2];
    const float* b1  = (const float*)d_in[3];
    const float* W2  = (const float*)d_in[4];
    const float* b2  = (const float*)d_in[5];
    const float* W3  = (const float*)d_in[6];
    const float* b3  = (const float*)d_in[7];
    float* out = (float*)d_out;

    const int N = in_sizes[0] / IN_DIM;   // 50000
    const int E = in_sizes[1] / 2;        // 800000
    const int* src = ei;
    const int* dst = ei + E;
    const int NBK  = (N + 255) / 256;     // buckets (196)
    const int BINB = (E + 4095) / 4096;   // bin blocks (196)

    // workspace layout
    char* ws = (char*)d_ws;
    size_t o = 0;
    int*       bkcnt = (int*)(ws + o);       o = align256(o + 256 * 4);
    int*       off   = (int*)(ws + o);       o = align256(o + (size_t)(N + 1) * 4);
    float*     dinv  = (float*)(ws + o);     o = align256(o + (size_t)N * 4);
    unsigned*  pairs = (unsigned*)(ws + o);  o = align256(o + (size_t)NBK * BCAP * 4);
    int*       col   = (int*)(ws + o);       o = align256(o + (size_t)E * 4);
    _Float16*  bufG  = (_Float16*)(ws + o);  o = align256(o + (size_t)N * HID_DIM * 2);
    _Float16*  bufH  = (_Float16*)(ws + o);  o = align256(o + (size_t)N * HID_DIM * 2);
    (void)ws_size;

    // CSR build
    hipMemsetAsync(bkcnt, 0, 256 * 4, stream);
    bin_kernel<<<BINB, 256, 0, stream>>>(src, dst, bkcnt, pairs, E);
    build_csr_kernel<<<NBK, 256, 0, stream>>>(pairs, bkcnt, off, dinv, col, N, NBK);

    const int g64_grid  = (N + 63) / 64;    // RT=64
    const int g32_grid  = (N + 127) / 128;  // RT=128
    const int agg64_grid = (N + 3) / 4;     // 1 node/wave, 4 waves/block
    const int agg32_grid = (N + 7) / 8;     // 2 nodes/wave, 4 waves/block

    // layer 1
    gemm_tile_kernel<HID_DIM, 64, float><<<g64_grid, 256, 0, stream>>>(x, W1, dinv, bufG, N);
    agg64_kernel<true><<<agg64_grid, 256, 0, stream>>>(bufG, off, col, dinv, b1, bufH, N);
    // layer 2
    gemm_tile_kernel<HID_DIM, 64, _Float16><<<g64_grid, 256, 0, stream>>>(bufH, W2, dinv, bufG, N);
    agg64_kernel<true><<<agg64_grid, 256, 0, stream>>>(bufG, off, col, dinv, b2, bufH, N);
    // layer 3 (D=32, f32 out)
    gemm_tile_kernel<LAT_DIM, 128, _Float16><<<g32_grid, 256, 0, stream>>>(bufH, W3, dinv, bufG, N);
    agg32_kernel<<<agg32_grid, 256, 0, stream>>>(bufG, off, col, dinv, b3, out, N);
}

// Round 11
// 202.352 us; speedup vs baseline: 1.2136x; 1.1161x over previous
//
#include <hip/hip_runtime.h>
#include <hip/hip_fp16.h>
#include <type_traits>

// 3-layer GCN encoder on MI355X.
//   CSR build: bin (bucket by dst>>8, packed src|localdst<<16) ->
//              build_csr (fused bucket-scan + LDS histogram + block scan -> off/dinv,
//                         then in-LDS scatter -> col)
//   Per layer: g = (h @ W) * dinv [fp16] ; h = act(dinv * sum_{N(d)+self} g[s] + b)
// R11: aggs repacked for 2x/4x node-level memory parallelism:
//      agg64 = 2 nodes/wave (32 lanes x half2 per node), agg32 = 4 nodes/wave
//      (16 lanes x half2). Same instruction count per edge; doubles concurrent
//      nodes/CU and outstanding gathers (R7 null-result says not BW-bound;
//      R10 says partially issue-bound; residual theory = latency-bound).
// NOTE: packing assumes N <= 65535 (here N=50000).

#define IN_DIM 64
#define HID_DIM 64
#define LAT_DIM 32
#define BCAP 5120   // bucket capacity: mean 4081, sigma ~64 -> +16 sigma

typedef __attribute__((ext_vector_type(8))) _Float16 half8;
typedef __attribute__((ext_vector_type(4))) _Float16 half4;

// ---------------- bucketed CSR construction ----------------

__global__ __launch_bounds__(256) void bin_kernel(const int* __restrict__ src,
                                                  const int* __restrict__ dst,
                                                  int* __restrict__ bucket_cnt,
                                                  unsigned* __restrict__ pairs, int E) {
    __shared__ int bcnt[256];
    __shared__ int bbase[256];
    int tid = threadIdx.x;
    bcnt[tid] = 0;
    __syncthreads();
    int base = blockIdx.x * 4096;
    unsigned pk[16]; int bk[16]; int rk[16];
    #pragma unroll
    for (int i = 0; i < 16; ++i) {
        int e = base + i * 256 + tid;
        bk[i] = -1;
        if (e < E) {
            int s = __builtin_nontemporal_load(src + e);
            int d = __builtin_nontemporal_load(dst + e);
            bk[i] = d >> 8;
            pk[i] = (unsigned)s | ((unsigned)(d & 255) << 16);
            rk[i] = atomicAdd(&bcnt[bk[i]], 1);
        }
    }
    __syncthreads();
    int c = bcnt[tid];
    if (c > 0) bbase[tid] = atomicAdd(&bucket_cnt[tid], c);
    __syncthreads();
    #pragma unroll
    for (int i = 0; i < 16; ++i) {
        if (bk[i] >= 0) {
            int pos = bbase[bk[i]] + rk[i];
            if (pos < BCAP) pairs[(size_t)bk[i] * BCAP + pos] = pk[i];
        }
    }
}

// Fused: (A) every block scans all bucket counts in LDS (cheap, redundant),
// (B) per-bucket node histogram, (C) block scan -> off/dinv, (D) in-LDS scatter.
__global__ __launch_bounds__(256) void build_csr_kernel(const unsigned* __restrict__ pairs,
                                                        const int* __restrict__ bucket_cnt,
                                                        int* __restrict__ off,
                                                        float* __restrict__ dinv,
                                                        int* __restrict__ col,
                                                        int N, int NBK) {
    __shared__ int sboff[256];
    __shared__ int h[256];
    __shared__ int scur[256];
    __shared__ int wtot[4];
    int b = blockIdx.x, tid = threadIdx.x;
    int lane = tid & 63, wid = tid >> 6;

    // A: exclusive scan of bucket counts
    int v = (tid < NBK) ? min(bucket_cnt[tid], BCAP) : 0;
    int sc = v;
    #pragma unroll
    for (int d = 1; d < 64; d <<= 1) {
        int t = __shfl_up(sc, d, 64);
        if (lane >= d) sc += t;
    }
    if (lane == 63) wtot[wid] = sc;
    h[tid] = 0;
    __syncthreads();
    int woff = 0;
    #pragma unroll
    for (int w = 0; w < 4; ++w) if (w < wid) woff += wtot[w];
    sboff[tid] = woff + sc - v;
    __syncthreads();
    int boff_b = sboff[b];

    // B: histogram of this bucket's local dst
    int c = min(bucket_cnt[b], BCAP);
    const unsigned* pb = pairs + (size_t)b * BCAP;
    for (int i = tid; i < c; i += 256)
        atomicAdd(&h[pb[i] >> 16], 1);
    __syncthreads();

    // C: block scan of histogram -> off / dinv / scur
    int hv = h[tid];
    int sc2 = hv;
    #pragma unroll
    for (int d = 1; d < 64; d <<= 1) {
        int t = __shfl_up(sc2, d, 64);
        if (lane >= d) sc2 += t;
    }
    if (lane == 63) wtot[wid] = sc2;
    __syncthreads();
    int woff2 = 0;
    #pragma unroll
    for (int w = 0; w < 4; ++w) if (w < wid) woff2 += wtot[w];
    int incl = woff2 + sc2;
    int node = b * 256 + tid;
    scur[tid] = boff_b + incl - hv;
    if (node < N) {
        off[node + 1] = boff_b + incl;
        dinv[node]    = rsqrtf((float)(hv + 1));
    }
    if (b == 0 && tid == 0) off[0] = 0;
    __syncthreads();

    // D: scatter (col writes land in this bucket's contiguous window)
    for (int i = tid; i < c; i += 256) {
        unsigned p = pb[i];
        int pos = atomicAdd(&scur[p >> 16], 1);
        col[pos] = (int)(p & 0xFFFFu);
    }
}

// ---------------- GEMM (N x 64) @ (64 x OUT) * dinv[row] -> fp16 G ----------------
// Row-major X staging (coalesced). 4x4 outputs/thread; a-reads are 16-lane
// broadcasts (free), b-read one 2-way b128 (free).

template<int OUT, int RT, typename TIN>
__global__ __launch_bounds__(256) void gemm_tile_kernel(const TIN* __restrict__ X,
                                                        const float* __restrict__ W,
                                                        const float* __restrict__ dinv,
                                                        _Float16* __restrict__ G, int N) {
    constexpr int CG = OUT / 4;
    static_assert(256 / CG * 4 == RT, "RT must match 4*(256/CG)");
    __shared__ float Ws[64 * OUT];
    __shared__ float Xs[RT][64 + 4];
    int tid = threadIdx.x;
    int row0 = blockIdx.x * RT;

    for (int f = 4 * tid; f < 64 * OUT; f += 1024)
        *(float4*)&Ws[f] = *(const float4*)&W[f];

    if constexpr (std::is_same<TIN, float>::value) {
        for (int f = 4 * tid; f < RT * 64; f += 1024) {
            int r = f >> 6, k0 = f & 63, gr = row0 + r;
            float4 v = (gr < N) ? *(const float4*)&X[(size_t)gr * 64 + k0]
                                : make_float4(0.f, 0.f, 0.f, 0.f);
            *(float4*)&Xs[r][k0] = v;
        }
    } else {
        for (int f = 8 * tid; f < RT * 64; f += 2048) {
            int r = f >> 6, k0 = f & 63, gr = row0 + r;
            if (gr < N) {
                half8 v = *(const half8*)&X[(size_t)gr * 64 + k0];
                #pragma unroll
                for (int i = 0; i < 8; ++i) Xs[r][k0 + i] = (float)v[i];
            } else {
                #pragma unroll
                for (int i = 0; i < 8; ++i) Xs[r][k0 + i] = 0.f;
            }
        }
    }
    __syncthreads();

    int cr = tid % CG;
    int rr = tid / CG;
    float acc[4][4] = {};
    #pragma unroll 4
    for (int k = 0; k < 64; ++k) {
        float4 bv = *(float4*)&Ws[k * OUT + 4 * cr];
        float av[4] = {Xs[4 * rr + 0][k], Xs[4 * rr + 1][k],
                       Xs[4 * rr + 2][k], Xs[4 * rr + 3][k]};
        float bb[4] = {bv.x, bv.y, bv.z, bv.w};
        #pragma unroll
        for (int j = 0; j < 4; ++j)
            #pragma unroll
            for (int i = 0; i < 4; ++i)
                acc[j][i] += av[j] * bb[i];
    }

    #pragma unroll
    for (int j = 0; j < 4; ++j) {
        int gr = row0 + 4 * rr + j;
        if (gr < N) {
            float s = dinv[gr];
            half4 o;
            #pragma unroll
            for (int i = 0; i < 4; ++i) o[i] = (_Float16)(acc[j][i] * s);
            *(half4*)&G[(size_t)gr * OUT + 4 * cr] = o;
        }
    }
}

// ---------------- CSR aggregation, half2 lanes, multi-node waves ----------------
// D=64: 2 nodes/wave. Lanes 0-31 = node A, 32-63 = node B; lane owns half2
// column pair. Per edge per lane: one 4B load (32 lanes x 4B = 128B coalesced
// row) + 2 cvt-adds. Doubles concurrent nodes/CU and outstanding gathers vs
// one-node-per-wave. Degree divergence between the two halves is exec-masked.

template<bool TANH>
__global__ __launch_bounds__(256) void agg64_kernel(const _Float16* __restrict__ G,
                           const int* __restrict__ off, const int* __restrict__ col,
                           const float* __restrict__ dinv, const float* __restrict__ b,
                           _Float16* __restrict__ H, int N) {
    int tid  = threadIdx.x;
    int lane = tid & 63;
    int w    = tid >> 6;
    int half = lane >> 5;
    int l2   = lane & 31;                       // half2 column index (row = 32 half2)
    int node = (blockIdx.x * 4 + w) * 2 + half;
    if (node >= N) return;
    const __half2* Gv = (const __half2*)G;
    int p  = off[node];
    int p1 = off[node + 1];
    float2 sf = __half22float2(Gv[(size_t)node * 32 + l2]);   // self loop
    float a0x = sf.x, a0y = sf.y;
    float a1x = 0.f, a1y = 0.f, a2x = 0.f, a2y = 0.f, a3x = 0.f, a3y = 0.f;
    for (; p + 3 < p1; p += 4) {
        int s0 = col[p], s1 = col[p + 1], s2 = col[p + 2], s3 = col[p + 3];
        float2 v0 = __half22float2(Gv[(size_t)s0 * 32 + l2]);
        float2 v1 = __half22float2(Gv[(size_t)s1 * 32 + l2]);
        float2 v2 = __half22float2(Gv[(size_t)s2 * 32 + l2]);
        float2 v3 = __half22float2(Gv[(size_t)s3 * 32 + l2]);
        a0x += v0.x; a0y += v0.y;
        a1x += v1.x; a1y += v1.y;
        a2x += v2.x; a2y += v2.y;
        a3x += v3.x; a3y += v3.y;
    }
    for (; p < p1; ++p) {
        float2 v = __half22float2(Gv[(size_t)col[p] * 32 + l2]);
        a0x += v.x; a0y += v.y;
    }
    float dn = dinv[node];
    float vx = dn * ((a0x + a1x) + (a2x + a3x)) + b[2 * l2 + 0];
    float vy = dn * ((a0y + a1y) + (a2y + a3y)) + b[2 * l2 + 1];
    if (TANH) { vx = tanhf(vx); vy = tanhf(vy); }
    ((__half2*)H)[(size_t)node * 32 + l2] = __floats2half2_rn(vx, vy);
}

// D=32 final layer: 4 nodes/wave (16 lanes x half2 each), f32 float2 output.
__global__ __launch_bounds__(256) void agg32_kernel(const _Float16* __restrict__ G,
                           const int* __restrict__ off, const int* __restrict__ col,
                           const float* __restrict__ dinv, const float* __restrict__ b,
                           float* __restrict__ H, int N) {
    int tid  = threadIdx.x;
    int lane = tid & 63;
    int w    = tid >> 6;
    int q    = lane >> 4;                       // node within wave (0..3)
    int l2   = lane & 15;                       // half2 column index (row = 16 half2)
    int node = (blockIdx.x * 4 + w) * 4 + q;
    if (node >= N) return;
    const __half2* Gv = (const __half2*)G;
    int p  = off[node];
    int p1 = off[node + 1];
    float2 sf = __half22float2(Gv[(size_t)node * 16 + l2]);   // self loop
    float a0x = sf.x, a0y = sf.y;
    float a1x = 0.f, a1y = 0.f, a2x = 0.f, a2y = 0.f, a3x = 0.f, a3y = 0.f;
    for (; p + 3 < p1; p += 4) {
        int s0 = col[p], s1 = col[p + 1], s2 = col[p + 2], s3 = col[p + 3];
        float2 v0 = __half22float2(Gv[(size_t)s0 * 16 + l2]);
        float2 v1 = __half22float2(Gv[(size_t)s1 * 16 + l2]);
        float2 v2 = __half22float2(Gv[(size_t)s2 * 16 + l2]);
        float2 v3 = __half22float2(Gv[(size_t)s3 * 16 + l2]);
        a0x += v0.x; a0y += v0.y;
        a1x += v1.x; a1y += v1.y;
        a2x += v2.x; a2y += v2.y;
        a3x += v3.x; a3y += v3.y;
    }
    for (; p < p1; ++p) {
        float2 v = __half22float2(Gv[(size_t)col[p] * 16 + l2]);
        a0x += v.x; a0y += v.y;
    }
    float dn = dinv[node];
    float vx = dn * ((a0x + a1x) + (a2x + a3x)) + b[2 * l2 + 0];
    float vy = dn * ((a0y + a1y) + (a2y + a3y)) + b[2 * l2 + 1];
    ((float2*)H)[(size_t)node * 16 + l2] = make_float2(vx, vy);
}

// ---------------- launch ----------------

static inline size_t align256(size_t x) { return (x + 255) & ~(size_t)255; }

extern "C" void kernel_launch(void* const* d_in, const int* in_sizes, int n_in,
                              void* d_out, int out_size, void* d_ws, size_t ws_size,
                              hipStream_t stream) {
    const float* x   = (const float*)d_in[0];
    const int*   ei  = (const int*)d_in[1];
    const float* W1  = (const float*)d_in[2];
    const float* b1  = (const float*)d_in[3];
    const float* W2  = (const float*)d_in[4];
    const float* b2  = (const float*)d_in[5];
    const float* W3  = (const float*)d_in[6];
    const float* b3  = (const float*)d_in[7];
    float* out = (float*)d_out;

    const int N = in_sizes[0] / IN_DIM;   // 50000
    const int E = in_sizes[1] / 2;        // 800000
    const int* src = ei;
    const int* dst = ei + E;
    const int NBK  = (N + 255) / 256;     // buckets (196)
    const int BINB = (E + 4095) / 4096;   // bin blocks (196)

    // workspace layout
    char* ws = (char*)d_ws;
    size_t o = 0;
    int*       bkcnt = (int*)(ws + o);       o = align256(o + 256 * 4);
    int*       off   = (int*)(ws + o);       o = align256(o + (size_t)(N + 1) * 4);
    float*     dinv  = (float*)(ws + o);     o = align256(o + (size_t)N * 4);
    unsigned*  pairs = (unsigned*)(ws + o);  o = align256(o + (size_t)NBK * BCAP * 4);
    int*       col   = (int*)(ws + o);       o = align256(o + (size_t)E * 4);
    _Float16*  bufG  = (_Float16*)(ws + o);  o = align256(o + (size_t)N * HID_DIM * 2);
    _Float16*  bufH  = (_Float16*)(ws + o);  o = align256(o + (size_t)N * HID_DIM * 2);
    (void)ws_size;

    // CSR build
    hipMemsetAsync(bkcnt, 0, 256 * 4, stream);
    bin_kernel<<<BINB, 256, 0, stream>>>(src, dst, bkcnt, pairs, E);
    build_csr_kernel<<<NBK, 256, 0, stream>>>(pairs, bkcnt, off, dinv, col, N, NBK);

    const int g64_grid   = (N + 63) / 64;    // RT=64
    const int g32_grid   = (N + 127) / 128;  // RT=128
    const int agg64_grid = (N + 7) / 8;      // 2 nodes/wave, 4 waves/block
    const int agg32_grid = (N + 15) / 16;    // 4 nodes/wave, 4 waves/block

    // layer 1
    gemm_tile_kernel<HID_DIM, 64, float><<<g64_grid, 256, 0, stream>>>(x, W1, dinv, bufG, N);
    agg64_kernel<true><<<agg64_grid, 256, 0, stream>>>(bufG, off, col, dinv, b1, bufH, N);
    // layer 2
    gemm_tile_kernel<HID_DIM, 64, _Float16><<<g64_grid, 256, 0, stream>>>(bufH, W2, dinv, bufG, N);
    agg64_kernel<true><<<agg64_grid, 256, 0, stream>>>(bufG, off, col, dinv, b2, bufH, N);
    // layer 3 (D=32, f32 out)
    gemm_tile_kernel<LAT_DIM, 128, _Float16><<<g32_grid, 256, 0, stream>>>(bufH, W3, dinv, bufG, N);
    agg32_kernel<<<agg32_grid, 256, 0, stream>>>(bufG, off, col, dinv, b3, out, N);
}